// Round 2
// baseline (14696.283 us; speedup 1.0000x reference)
//
#include <hip/hip_runtime.h>

// Fsmm_rnn: 2-layer tanh RNN (B=64,T=2048,D=4,H=256) + closed-form last-step
// grad + fractional-memory Up at t=T-1 + (64,64) broadcast assemblies.
//
// v2: 512 threads/block (8 waves, 2/SIMD). Thread (j,half) holds HALF-rows
// (128 cols -> 64 h2 regs each) of Whh0, Wih1, Whh1 => 192 weight VGPRs,
// fits the 256-VGPR/wave budget at 2 waves/EU (v1 spilled 384 regs to
// scratch: VGPR_Count=208, 6% VALUBusy, latency-bound).
// Fused step: given {h0[t], h1[t-1]} compute h1[t] AND h0[t+1] in one pass
// (e-dot and a-dot share the h0[t] broadcast reads); 2 barriers/step.

#define TT 2048
#define HH 256
#define WIN 64

typedef _Float16 h2 __attribute__((ext_vector_type(2)));

__device__ __forceinline__ float fdot2p(h2 a, h2 b, float c) {
  return __builtin_amdgcn_fdot2(a, b, c, false);
}
__device__ __forceinline__ h2 bc2(unsigned u) {
  return __builtin_bit_cast(h2, u);
}

__device__ __forceinline__ float tanh_fast(float x) {
  float xc = fminf(fmaxf(x, -15.f), 15.f);
  float e = __expf(2.f * xc);
  return (e - 1.f) * __builtin_amdgcn_rcpf(e + 1.f);
}

// 512-thread (8-wave) block sum, broadcast to all threads.
__device__ __forceinline__ float block_sum8(float v, float* red, int tid) {
#pragma unroll
  for (int off = 32; off >= 1; off >>= 1) v += __shfl_down(v, off, 64);
  __syncthreads();  // protect red reuse across calls
  if ((tid & 63) == 0) red[tid >> 6] = v;
  __syncthreads();
  float s = 0.f;
#pragma unroll
  for (int w = 0; w < 8; ++w) s += red[w];
  return s;
}

// 128-col half-row dot vs broadcast h vector (16 uint4 uniform LDS reads).
#define DOTHALF(WARR, HP, A0, A1, A2, A3)                                  \
  {                                                                        \
    _Pragma("unroll") for (int _i = 0; _i < 16; ++_i) {                    \
      uint4 _u = (HP)[_i];                                                 \
      A0 = fdot2p(WARR[4 * _i + 0], bc2(_u.x), A0);                        \
      A1 = fdot2p(WARR[4 * _i + 1], bc2(_u.y), A1);                        \
      A2 = fdot2p(WARR[4 * _i + 2], bc2(_u.z), A2);                        \
      A3 = fdot2p(WARR[4 * _i + 3], bc2(_u.w), A3);                        \
    }                                                                      \
  }

__global__ __launch_bounds__(512, 2) void rnn_chain_kernel(
    const float* __restrict__ x, const float* __restrict__ Wih0,
    const float* __restrict__ Whh0, const float* __restrict__ bih0,
    const float* __restrict__ bhh0, const float* __restrict__ Wih1,
    const float* __restrict__ Whh1, const float* __restrict__ bih1,
    const float* __restrict__ bhh1, const float* __restrict__ fcW,
    const float* __restrict__ fcb, const float* __restrict__ f1W,
    const float* __restrict__ f1b, const float* __restrict__ f2W,
    const float* __restrict__ f2b, const float* __restrict__ C1,
    const float* __restrict__ R1, const float* __restrict__ binom,
    float* __restrict__ out_soc,  // d_out[0..64)
    float* __restrict__ ws)       // [0..64) d_soc, [64..128) f_soc, [128..192) Up_last
{
  const int b = blockIdx.x;
  const int tid = threadIdx.x;
  const int j = tid & 255;      // row
  const int half = tid >> 8;    // 0: cols 0..127, 1: cols 128..255

  __shared__ __align__(16) float xs[TT * 4];      // 32 KB: whole x[b]
  __shared__ __align__(16) _Float16 h0L[HH];      // current h0 (f16)
  __shared__ __align__(16) _Float16 h1L[HH];      // current h1 (f16)
  __shared__ float sZ1[HH];  // half0's partial of z1 (e+c)
  __shared__ float sZ0[HH];  // half1's partial of z0 (a)
  __shared__ float red[8];
  __shared__ float uL[HH];

  // ---- preload x[b] into LDS (coalesced float4) ----
  const float4* xg = (const float4*)(x + (size_t)b * TT * 4);
  float4* xl = (float4*)xs;
  for (int i = tid; i < TT; i += 512) xl[i] = xg[i];

  // ---- load + convert half-rows into registers (f16 packed, 192 VGPRs) ----
  h2 w0[64], w1i[64], w1h[64];
  {
    const float4* g0 = (const float4*)(Whh0 + (size_t)j * HH + half * 128);
#pragma unroll
    for (int i = 0; i < 32; ++i) {
      float4 a = g0[i];
      h2 t0; t0.x = (_Float16)a.x; t0.y = (_Float16)a.y; w0[2 * i] = t0;
      h2 t1; t1.x = (_Float16)a.z; t1.y = (_Float16)a.w; w0[2 * i + 1] = t1;
    }
    const float4* g1 = (const float4*)(Wih1 + (size_t)j * HH + half * 128);
#pragma unroll
    for (int i = 0; i < 32; ++i) {
      float4 a = g1[i];
      h2 t0; t0.x = (_Float16)a.x; t0.y = (_Float16)a.y; w1i[2 * i] = t0;
      h2 t1; t1.x = (_Float16)a.z; t1.y = (_Float16)a.w; w1i[2 * i + 1] = t1;
    }
    const float4* g2 = (const float4*)(Whh1 + (size_t)j * HH + half * 128);
#pragma unroll
    for (int i = 0; i < 32; ++i) {
      float4 a = g2[i];
      h2 t0; t0.x = (_Float16)a.x; t0.y = (_Float16)a.y; w1h[2 * i] = t0;
      h2 t1; t1.x = (_Float16)a.z; t1.y = (_Float16)a.w; w1h[2 * i + 1] = t1;
    }
  }
  const float4 wx = ((const float4*)Wih0)[j];  // row j of Wih0 (D=4)
  const float bias0 = bih0[j] + bhh0[j];
  const float bias1 = bih1[j] + bhh1[j];

  __syncthreads();  // xs ready

  // ---- prologue: h0[0] = tanh(Wih0 x0 + b0), h1[-1] = 0 ----
  if (half == 0) {
    float4 x0v = xl[0];
    float z = wx.x * x0v.x + wx.y * x0v.y + wx.z * x0v.z + wx.w * x0v.w + bias0;
    h0L[j] = (_Float16)tanh_fast(z);
    h1L[j] = (_Float16)0.f;
  }
  __syncthreads();

  const uint4* h0p = (const uint4*)h0L + half * 16;
  const uint4* h1p = (const uint4*)h1L + half * 16;

  float h0T = 0.f;  // half0: f32 h0[T-1]
  float h1T = 0.f;  // half1: f32 h1[T-1]

  // ---- fused scan: iteration t computes h1[t] and h0[t+1]; t = 0..T-2 ----
  for (int t = 0; t < TT - 1; ++t) {
    float e0 = 0, e1 = 0, e2 = 0, e3 = 0;
    float a0 = 0, a1 = 0, a2 = 0, a3 = 0;
    float c0 = 0, c1 = 0, c2 = 0, c3 = 0;
    // shared pass over h0[t]: e (Wih1) and a (Whh0)
#pragma unroll
    for (int i = 0; i < 16; ++i) {
      uint4 u = h0p[i];
      e0 = fdot2p(w1i[4 * i + 0], bc2(u.x), e0);
      a0 = fdot2p(w0[4 * i + 0], bc2(u.x), a0);
      e1 = fdot2p(w1i[4 * i + 1], bc2(u.y), e1);
      a1 = fdot2p(w0[4 * i + 1], bc2(u.y), a1);
      e2 = fdot2p(w1i[4 * i + 2], bc2(u.z), e2);
      a2 = fdot2p(w0[4 * i + 2], bc2(u.z), a2);
      e3 = fdot2p(w1i[4 * i + 3], bc2(u.w), e3);
      a3 = fdot2p(w0[4 * i + 3], bc2(u.w), a3);
    }
    DOTHALF(w1h, h1p, c0, c1, c2, c3);
    float e = (e0 + e1) + (e2 + e3);
    float a = (a0 + a1) + (a2 + a3);
    float c = (c0 + c1) + (c2 + c3);
    if (half == 0) sZ1[j] = e + c;  // wave-uniform branch
    else           sZ0[j] = a;
    __syncthreads();
    if (half == 1) {
      float z1 = e + c + sZ1[j] + bias1;
      h1T = tanh_fast(z1);
      h1L[j] = (_Float16)h1T;
    } else {
      float4 xt = xl[t + 1];
      float z0 = a + sZ0[j] + wx.x * xt.x + wx.y * xt.y + wx.z * xt.z +
                 wx.w * xt.w + bias0;
      h0T = tanh_fast(z0);
      h0L[j] = (_Float16)h0T;
    }
    __syncthreads();
  }

  // ---- final step: h1[T-1] only ----
  {
    float e0 = 0, e1 = 0, e2 = 0, e3 = 0;
    float c0 = 0, c1 = 0, c2 = 0, c3 = 0;
    DOTHALF(w1i, h0p, e0, e1, e2, e3);
    DOTHALF(w1h, h1p, c0, c1, c2, c3);
    float ec = ((e0 + e1) + (e2 + e3)) + ((c0 + c1) + (c2 + c3));
    if (half == 0) sZ1[j] = ec;
    __syncthreads();
    if (half == 1) {
      float z1 = ec + sZ1[j] + bias1;
      h1T = tanh_fast(z1);
      h1L[j] = (_Float16)h1T;
    }
    __syncthreads();
  }
  // Now: half0 threads hold f32 h0T = h0[T-1]; half1 threads hold f32 h1T.

  // ---- epilogue ----
  const float fw = fcW[j];

  float socb = block_sum8(half == 1 ? fw * h1T : 0.f, red, tid) + fcb[0];
  if (tid == 0) out_soc[b] = socb;

  float fsv = (half == 1) ? f2W[j] * (socb * f1W[j] + f1b[j]) : 0.f;
  float fsb = block_sum8(fsv, red, tid) + f2b[0];
  if (tid == 0) ws[64 + b] = fsb;

  // d_soc: u[k] = fcW[k](1-h1T[k]^2); g[h] = sum_k u[k] Wih1[k,h];
  //        dsoc = sum_h g[h] (1-h0T[h]^2) Wih0[h,3]
  if (half == 1) uL[j] = fw * (1.f - h1T * h1T);
  __syncthreads();
  float g = 0.f;
  {
    const int k0 = half * 128;
#pragma unroll 8
    for (int k = 0; k < 128; ++k)
      g += uL[k0 + k] * Wih1[(size_t)(k0 + k) * HH + j];
  }
  if (half == 1) sZ0[j] = g;
  __syncthreads();
  float dsv = 0.f;
  if (half == 0) dsv = (g + sZ0[j]) * (1.f - h0T * h0T) * wx.w;
  float dsoc = block_sum8(dsv, red, tid);
  if (tid == 0) ws[b] = dsoc;

  // Up[:, -1]: Ts = sqrt((time[T-1]-time[T-64])/63); hist = sum binom[k+1]*v[T-64+k]
  float histv = 0.f;
  if (tid < WIN) histv = binom[tid + 1] * xs[(TT - WIN + tid) * 4 + 0];
  float hist = block_sum8(histv, red, tid);
  if (tid == 0) {
    float tl = xs[(TT - 1) * 4 + 3], t0v = xs[(TT - WIN) * 4 + 3];
    float tdiff = (tl - t0v) * (1.0f / (float)(WIN - 1));
    float Ts = sqrtf(tdiff);
    float vlast = xs[(TT - 1) * 4 + 0], Ilast = xs[(TT - 1) * 4 + 1];
    float r1 = R1[0], c1v = C1[0];
    float up = -Ts / (r1 * c1v) * vlast + Ts / c1v * Ilast - hist;
    ws[128 + b] = up;
  }
}

__global__ void assemble_kernel(const float* __restrict__ x,
                                const float* __restrict__ Q,
                                const float* __restrict__ delta,
                                const float* __restrict__ R0,
                                const float* __restrict__ ws,
                                float* __restrict__ out) {
  const int i = blockIdx.x;    // row (batch)
  const int jj = threadIdx.x;  // col 0..63
  const float dq = delta[0] / Q[0];
  const size_t base = ((size_t)i * TT + (TT - 1)) * 4;
  const float xv0 = x[base + 0];
  const float xv1 = x[base + 1];
  const float fs = ws[64 + i];
  // loss1[i,j] = delta/Q * x[i,-1,1] + d_soc[j]
  out[64 + i * 64 + jj] = dq * xv1 + ws[jj];
  // loss2[i,j] = f_soc[i] - x[i,-1,0] - R0*x[i,-1,1] - Up_last[j]
  out[64 + 4096 + i * 64 + jj] = fs - xv0 - R0[0] * xv1 - ws[128 + jj];
}

extern "C" void kernel_launch(void* const* d_in, const int* in_sizes, int n_in,
                              void* d_out, int out_size, void* d_ws,
                              size_t ws_size, hipStream_t stream) {
  const float* x    = (const float*)d_in[0];
  const float* Wih0 = (const float*)d_in[1];
  const float* Whh0 = (const float*)d_in[2];
  const float* bih0 = (const float*)d_in[3];
  const float* bhh0 = (const float*)d_in[4];
  const float* Wih1 = (const float*)d_in[5];
  const float* Whh1 = (const float*)d_in[6];
  const float* bih1 = (const float*)d_in[7];
  const float* bhh1 = (const float*)d_in[8];
  const float* fcW  = (const float*)d_in[9];
  const float* fcb  = (const float*)d_in[10];
  const float* Q    = (const float*)d_in[11];
  const float* delta= (const float*)d_in[12];
  const float* f1W  = (const float*)d_in[13];
  const float* f1b  = (const float*)d_in[14];
  const float* f2W  = (const float*)d_in[15];
  const float* f2b  = (const float*)d_in[16];
  // d_in[17] = U0 (unused by reference)
  const float* R0   = (const float*)d_in[18];
  const float* C1   = (const float*)d_in[19];
  const float* R1   = (const float*)d_in[20];
  const float* binom= (const float*)d_in[21];

  float* out = (float*)d_out;
  float* ws  = (float*)d_ws;

  hipLaunchKernelGGL(rnn_chain_kernel, dim3(64), dim3(512), 0, stream, x, Wih0,
                     Whh0, bih0, bhh0, Wih1, Whh1, bih1, bhh1, fcW, fcb, f1W,
                     f1b, f2W, f2b, C1, R1, binom, out, ws);
  hipLaunchKernelGGL(assemble_kernel, dim3(64), dim3(64), 0, stream, x, Q,
                     delta, R0, ws, out);
}

// Round 4
// 14621.330 us; speedup vs baseline: 1.0051x; 1.0051x over previous
//
#include <hip/hip_runtime.h>

// Fsmm_rnn: 2-layer tanh RNN (B=64,T=2048,D=4,H=256) + closed-form last-step
// grad + fractional-memory Up at t=T-1 + (64,64) broadcast assemblies.
//
// v3 (resubmit — R3 was a GPU-acquisition timeout, no data): identical
// structure to v2 (512 thr = 8 waves; thread (j,half) holds 128-col
// half-rows of Whh0/Wih1/Whh1 = 192 h2 VGPRs; fused step, 2 barriers/step).
// ONLY change vs v2: register budget. v2's __launch_bounds__(512,2) was
// taken as min-2-blocks/CU -> 128-VGPR cap -> full spill (VGPR_Count=128,
// WRITE_SIZE=42MB scratch traffic, 2.7% VALUBusy). Now pin exactly 2
// waves/EU via amdgpu_waves_per_eu(2,2) -> 256-VGPR cap; demand ~230.

#define TT 2048
#define HH 256
#define WIN 64

typedef _Float16 h2 __attribute__((ext_vector_type(2)));

__device__ __forceinline__ float fdot2p(h2 a, h2 b, float c) {
  return __builtin_amdgcn_fdot2(a, b, c, false);
}
__device__ __forceinline__ h2 bc2(unsigned u) {
  return __builtin_bit_cast(h2, u);
}

__device__ __forceinline__ float tanh_fast(float x) {
  float xc = fminf(fmaxf(x, -15.f), 15.f);
  float e = __expf(2.f * xc);
  return (e - 1.f) * __builtin_amdgcn_rcpf(e + 1.f);
}

// 512-thread (8-wave) block sum, broadcast to all threads.
__device__ __forceinline__ float block_sum8(float v, float* red, int tid) {
#pragma unroll
  for (int off = 32; off >= 1; off >>= 1) v += __shfl_down(v, off, 64);
  __syncthreads();  // protect red reuse across calls
  if ((tid & 63) == 0) red[tid >> 6] = v;
  __syncthreads();
  float s = 0.f;
#pragma unroll
  for (int w = 0; w < 8; ++w) s += red[w];
  return s;
}

// 128-col half-row dot vs broadcast h vector (16 uint4 uniform LDS reads).
#define DOTHALF(WARR, HP, A0, A1, A2, A3)                                  \
  {                                                                        \
    _Pragma("unroll") for (int _i = 0; _i < 16; ++_i) {                    \
      uint4 _u = (HP)[_i];                                                 \
      A0 = fdot2p(WARR[4 * _i + 0], bc2(_u.x), A0);                        \
      A1 = fdot2p(WARR[4 * _i + 1], bc2(_u.y), A1);                        \
      A2 = fdot2p(WARR[4 * _i + 2], bc2(_u.z), A2);                        \
      A3 = fdot2p(WARR[4 * _i + 3], bc2(_u.w), A3);                        \
    }                                                                      \
  }

__global__ __launch_bounds__(512, 1)
__attribute__((amdgpu_waves_per_eu(2, 2)))
void rnn_chain_kernel(
    const float* __restrict__ x, const float* __restrict__ Wih0,
    const float* __restrict__ Whh0, const float* __restrict__ bih0,
    const float* __restrict__ bhh0, const float* __restrict__ Wih1,
    const float* __restrict__ Whh1, const float* __restrict__ bih1,
    const float* __restrict__ bhh1, const float* __restrict__ fcW,
    const float* __restrict__ fcb, const float* __restrict__ f1W,
    const float* __restrict__ f1b, const float* __restrict__ f2W,
    const float* __restrict__ f2b, const float* __restrict__ C1,
    const float* __restrict__ R1, const float* __restrict__ binom,
    float* __restrict__ out_soc,  // d_out[0..64)
    float* __restrict__ ws)       // [0..64) d_soc, [64..128) f_soc, [128..192) Up_last
{
  const int b = blockIdx.x;
  const int tid = threadIdx.x;
  const int j = tid & 255;      // row
  const int half = tid >> 8;    // 0: cols 0..127, 1: cols 128..255

  __shared__ __align__(16) float xs[TT * 4];      // 32 KB: whole x[b]
  __shared__ __align__(16) _Float16 h0L[HH];      // current h0 (f16)
  __shared__ __align__(16) _Float16 h1L[HH];      // current h1 (f16)
  __shared__ float sZ1[HH];  // half0's partial of z1 (e+c)
  __shared__ float sZ0[HH];  // half1's partial of z0 (a)
  __shared__ float red[8];
  __shared__ float uL[HH];

  // ---- preload x[b] into LDS (coalesced float4) ----
  const float4* xg = (const float4*)(x + (size_t)b * TT * 4);
  float4* xl = (float4*)xs;
  for (int i = tid; i < TT; i += 512) xl[i] = xg[i];

  // ---- load + convert half-rows into registers (f16 packed, 192 VGPRs) ----
  h2 w0[64], w1i[64], w1h[64];
  {
    const float4* g0 = (const float4*)(Whh0 + (size_t)j * HH + half * 128);
#pragma unroll
    for (int i = 0; i < 32; ++i) {
      float4 a = g0[i];
      h2 t0; t0.x = (_Float16)a.x; t0.y = (_Float16)a.y; w0[2 * i] = t0;
      h2 t1; t1.x = (_Float16)a.z; t1.y = (_Float16)a.w; w0[2 * i + 1] = t1;
    }
    const float4* g1 = (const float4*)(Wih1 + (size_t)j * HH + half * 128);
#pragma unroll
    for (int i = 0; i < 32; ++i) {
      float4 a = g1[i];
      h2 t0; t0.x = (_Float16)a.x; t0.y = (_Float16)a.y; w1i[2 * i] = t0;
      h2 t1; t1.x = (_Float16)a.z; t1.y = (_Float16)a.w; w1i[2 * i + 1] = t1;
    }
    const float4* g2 = (const float4*)(Whh1 + (size_t)j * HH + half * 128);
#pragma unroll
    for (int i = 0; i < 32; ++i) {
      float4 a = g2[i];
      h2 t0; t0.x = (_Float16)a.x; t0.y = (_Float16)a.y; w1h[2 * i] = t0;
      h2 t1; t1.x = (_Float16)a.z; t1.y = (_Float16)a.w; w1h[2 * i + 1] = t1;
    }
  }
  const float4 wx = ((const float4*)Wih0)[j];  // row j of Wih0 (D=4)
  const float bias0 = bih0[j] + bhh0[j];
  const float bias1 = bih1[j] + bhh1[j];

  __syncthreads();  // xs ready

  // ---- prologue: h0[0] = tanh(Wih0 x0 + b0), h1[-1] = 0 ----
  if (half == 0) {
    float4 x0v = xl[0];
    float z = wx.x * x0v.x + wx.y * x0v.y + wx.z * x0v.z + wx.w * x0v.w + bias0;
    h0L[j] = (_Float16)tanh_fast(z);
    h1L[j] = (_Float16)0.f;
  }
  __syncthreads();

  const uint4* h0p = (const uint4*)h0L + half * 16;
  const uint4* h1p = (const uint4*)h1L + half * 16;

  float h0T = 0.f;  // half0: f32 h0[T-1]
  float h1T = 0.f;  // half1: f32 h1[T-1]

  // ---- fused scan: iteration t computes h1[t] and h0[t+1]; t = 0..T-2 ----
  for (int t = 0; t < TT - 1; ++t) {
    float e0 = 0, e1 = 0, e2 = 0, e3 = 0;
    float a0 = 0, a1 = 0, a2 = 0, a3 = 0;
    float c0 = 0, c1 = 0, c2 = 0, c3 = 0;
    // shared pass over h0[t]: e (Wih1) and a (Whh0)
#pragma unroll
    for (int i = 0; i < 16; ++i) {
      uint4 u = h0p[i];
      e0 = fdot2p(w1i[4 * i + 0], bc2(u.x), e0);
      a0 = fdot2p(w0[4 * i + 0], bc2(u.x), a0);
      e1 = fdot2p(w1i[4 * i + 1], bc2(u.y), e1);
      a1 = fdot2p(w0[4 * i + 1], bc2(u.y), a1);
      e2 = fdot2p(w1i[4 * i + 2], bc2(u.z), e2);
      a2 = fdot2p(w0[4 * i + 2], bc2(u.z), a2);
      e3 = fdot2p(w1i[4 * i + 3], bc2(u.w), e3);
      a3 = fdot2p(w0[4 * i + 3], bc2(u.w), a3);
    }
    DOTHALF(w1h, h1p, c0, c1, c2, c3);
    float e = (e0 + e1) + (e2 + e3);
    float a = (a0 + a1) + (a2 + a3);
    float c = (c0 + c1) + (c2 + c3);
    if (half == 0) sZ1[j] = e + c;  // wave-uniform branch
    else           sZ0[j] = a;
    __syncthreads();
    if (half == 1) {
      float z1 = e + c + sZ1[j] + bias1;
      h1T = tanh_fast(z1);
      h1L[j] = (_Float16)h1T;
    } else {
      float4 xt = xl[t + 1];
      float z0 = a + sZ0[j] + wx.x * xt.x + wx.y * xt.y + wx.z * xt.z +
                 wx.w * xt.w + bias0;
      h0T = tanh_fast(z0);
      h0L[j] = (_Float16)h0T;
    }
    __syncthreads();
  }

  // ---- final step: h1[T-1] only ----
  {
    float e0 = 0, e1 = 0, e2 = 0, e3 = 0;
    float c0 = 0, c1 = 0, c2 = 0, c3 = 0;
    DOTHALF(w1i, h0p, e0, e1, e2, e3);
    DOTHALF(w1h, h1p, c0, c1, c2, c3);
    float ec = ((e0 + e1) + (e2 + e3)) + ((c0 + c1) + (c2 + c3));
    if (half == 0) sZ1[j] = ec;
    __syncthreads();
    if (half == 1) {
      float z1 = ec + sZ1[j] + bias1;
      h1T = tanh_fast(z1);
      h1L[j] = (_Float16)h1T;
    }
    __syncthreads();
  }
  // Now: half0 threads hold f32 h0T = h0[T-1]; half1 threads hold f32 h1T.

  // ---- epilogue ----
  const float fw = fcW[j];

  float socb = block_sum8(half == 1 ? fw * h1T : 0.f, red, tid) + fcb[0];
  if (tid == 0) out_soc[b] = socb;

  float fsv = (half == 1) ? f2W[j] * (socb * f1W[j] + f1b[j]) : 0.f;
  float fsb = block_sum8(fsv, red, tid) + f2b[0];
  if (tid == 0) ws[64 + b] = fsb;

  // d_soc: u[k] = fcW[k](1-h1T[k]^2); g[h] = sum_k u[k] Wih1[k,h];
  //        dsoc = sum_h g[h] (1-h0T[h]^2) Wih0[h,3]
  if (half == 1) uL[j] = fw * (1.f - h1T * h1T);
  __syncthreads();
  float g = 0.f;
  {
    const int k0 = half * 128;
#pragma unroll 8
    for (int k = 0; k < 128; ++k)
      g += uL[k0 + k] * Wih1[(size_t)(k0 + k) * HH + j];
  }
  if (half == 1) sZ0[j] = g;
  __syncthreads();
  float dsv = 0.f;
  if (half == 0) dsv = (g + sZ0[j]) * (1.f - h0T * h0T) * wx.w;
  float dsoc = block_sum8(dsv, red, tid);
  if (tid == 0) ws[b] = dsoc;

  // Up[:, -1]: Ts = sqrt((time[T-1]-time[T-64])/63); hist = sum binom[k+1]*v[T-64+k]
  float histv = 0.f;
  if (tid < WIN) histv = binom[tid + 1] * xs[(TT - WIN + tid) * 4 + 0];
  float hist = block_sum8(histv, red, tid);
  if (tid == 0) {
    float tl = xs[(TT - 1) * 4 + 3], t0v = xs[(TT - WIN) * 4 + 3];
    float tdiff = (tl - t0v) * (1.0f / (float)(WIN - 1));
    float Ts = sqrtf(tdiff);
    float vlast = xs[(TT - 1) * 4 + 0], Ilast = xs[(TT - 1) * 4 + 1];
    float r1 = R1[0], c1v = C1[0];
    float up = -Ts / (r1 * c1v) * vlast + Ts / c1v * Ilast - hist;
    ws[128 + b] = up;
  }
}

__global__ void assemble_kernel(const float* __restrict__ x,
                                const float* __restrict__ Q,
                                const float* __restrict__ delta,
                                const float* __restrict__ R0,
                                const float* __restrict__ ws,
                                float* __restrict__ out) {
  const int i = blockIdx.x;    // row (batch)
  const int jj = threadIdx.x;  // col 0..63
  const float dq = delta[0] / Q[0];
  const size_t base = ((size_t)i * TT + (TT - 1)) * 4;
  const float xv0 = x[base + 0];
  const float xv1 = x[base + 1];
  const float fs = ws[64 + i];
  // loss1[i,j] = delta/Q * x[i,-1,1] + d_soc[j]
  out[64 + i * 64 + jj] = dq * xv1 + ws[jj];
  // loss2[i,j] = f_soc[i] - x[i,-1,0] - R0*x[i,-1,1] - Up_last[j]
  out[64 + 4096 + i * 64 + jj] = fs - xv0 - R0[0] * xv1 - ws[128 + jj];
}

extern "C" void kernel_launch(void* const* d_in, const int* in_sizes, int n_in,
                              void* d_out, int out_size, void* d_ws,
                              size_t ws_size, hipStream_t stream) {
  const float* x    = (const float*)d_in[0];
  const float* Wih0 = (const float*)d_in[1];
  const float* Whh0 = (const float*)d_in[2];
  const float* bih0 = (const float*)d_in[3];
  const float* bhh0 = (const float*)d_in[4];
  const float* Wih1 = (const float*)d_in[5];
  const float* Whh1 = (const float*)d_in[6];
  const float* bih1 = (const float*)d_in[7];
  const float* bhh1 = (const float*)d_in[8];
  const float* fcW  = (const float*)d_in[9];
  const float* fcb  = (const float*)d_in[10];
  const float* Q    = (const float*)d_in[11];
  const float* delta= (const float*)d_in[12];
  const float* f1W  = (const float*)d_in[13];
  const float* f1b  = (const float*)d_in[14];
  const float* f2W  = (const float*)d_in[15];
  const float* f2b  = (const float*)d_in[16];
  // d_in[17] = U0 (unused by reference)
  const float* R0   = (const float*)d_in[18];
  const float* C1   = (const float*)d_in[19];
  const float* R1   = (const float*)d_in[20];
  const float* binom= (const float*)d_in[21];

  float* out = (float*)d_out;
  float* ws  = (float*)d_ws;

  hipLaunchKernelGGL(rnn_chain_kernel, dim3(64), dim3(512), 0, stream, x, Wih0,
                     Whh0, bih0, bhh0, Wih1, Whh1, bih1, bhh1, fcW, fcb, f1W,
                     f1b, f2W, f2b, C1, R1, binom, out, ws);
  hipLaunchKernelGGL(assemble_kernel, dim3(64), dim3(64), 0, stream, x, Q,
                     delta, R0, ws, out);
}

// Round 5
// 2882.801 us; speedup vs baseline: 5.0979x; 5.0719x over previous
//
#include <hip/hip_runtime.h>

// Fsmm_rnn: 2-layer tanh RNN (B=64,T=2048,D=4,H=256) + closed-form last-step
// grad + fractional-memory Up at t=T-1 + (64,64) broadcast assemblies.
//
// v4: QUARTER-row split, 1024 thr/block (16 waves, 4/SIMD -> natural 128-VGPR
// cap). Thread (q,j) holds 64-col quarter-rows of Whh0/Wih1/Whh1 as THREE
// ext_vector_type(32)-uint SSA values (96 VGPRs, cannot become scratch
// allocas). v2/v3 post-mortem: allocator pinned 8-wave blocks at 128 VGPRs,
// spilled 192-reg arrays -> 42MB scratch, L2-BW-bound at 7.15us/step
// (= 25MB/step / 34.5TB/s). Now demand ~120 <= cap 128.
// Cross-quarter reduce via LDS planes pZ[q][j]; 2 barriers/step.

#define TT 2048
#define HH 256
#define WIN 64

typedef _Float16 h2 __attribute__((ext_vector_type(2)));
typedef uint uvec32 __attribute__((ext_vector_type(32)));

__device__ __forceinline__ float fdot2p(h2 a, h2 b, float c) {
  return __builtin_amdgcn_fdot2(a, b, c, false);
}
__device__ __forceinline__ h2 bc2(unsigned u) {
  return __builtin_bit_cast(h2, u);
}

__device__ __forceinline__ float tanh_fast(float x) {
  float xc = fminf(fmaxf(x, -15.f), 15.f);
  float e = __expf(2.f * xc);
  return (e - 1.f) * __builtin_amdgcn_rcpf(e + 1.f);
}

// 1024-thread (16-wave) block sum, broadcast to all threads.
__device__ __forceinline__ float block_sum16(float v, float* red, int tid) {
#pragma unroll
  for (int off = 32; off >= 1; off >>= 1) v += __shfl_down(v, off, 64);
  __syncthreads();  // protect red reuse across calls
  if ((tid & 63) == 0) red[tid >> 6] = v;
  __syncthreads();
  float s = 0.f;
#pragma unroll
  for (int w = 0; w < 16; ++w) s += red[w];
  return s;
}

// Load+convert a 64-col quarter row (f32 global) into packed-h2 uvec32 (32 VGPRs).
__device__ __forceinline__ uvec32 ld_quarter(const float* __restrict__ base) {
  uvec32 w;
  const float4* g = (const float4*)base;
#pragma unroll
  for (int i = 0; i < 16; ++i) {
    float4 a = g[i];
    h2 t0; t0.x = (_Float16)a.x; t0.y = (_Float16)a.y;
    h2 t1; t1.x = (_Float16)a.z; t1.y = (_Float16)a.w;
    w[2 * i] = __builtin_bit_cast(uint, t0);
    w[2 * i + 1] = __builtin_bit_cast(uint, t1);
  }
  return w;
}

// 64-col quarter dot vs broadcast h vector (8 uint4 uniform LDS reads).
#define DOTQ(WV, HP, A0, A1, A2, A3)                                       \
  {                                                                        \
    _Pragma("unroll") for (int _i = 0; _i < 8; ++_i) {                     \
      uint4 _u = (HP)[_i];                                                 \
      A0 = fdot2p(bc2(WV[4 * _i + 0]), bc2(_u.x), A0);                     \
      A1 = fdot2p(bc2(WV[4 * _i + 1]), bc2(_u.y), A1);                     \
      A2 = fdot2p(bc2(WV[4 * _i + 2]), bc2(_u.z), A2);                     \
      A3 = fdot2p(bc2(WV[4 * _i + 3]), bc2(_u.w), A3);                     \
    }                                                                      \
  }

__global__ __launch_bounds__(1024) void rnn_chain_kernel(
    const float* __restrict__ x, const float* __restrict__ Wih0,
    const float* __restrict__ Whh0, const float* __restrict__ bih0,
    const float* __restrict__ bhh0, const float* __restrict__ Wih1,
    const float* __restrict__ Whh1, const float* __restrict__ bih1,
    const float* __restrict__ bhh1, const float* __restrict__ fcW,
    const float* __restrict__ fcb, const float* __restrict__ f1W,
    const float* __restrict__ f1b, const float* __restrict__ f2W,
    const float* __restrict__ f2b, const float* __restrict__ C1,
    const float* __restrict__ R1, const float* __restrict__ binom,
    float* __restrict__ out_soc,  // d_out[0..64)
    float* __restrict__ ws)       // [0..64) d_soc, [64..128) f_soc, [128..192) Up_last
{
  const int b = blockIdx.x;
  const int tid = threadIdx.x;
  const int j = tid & 255;    // row
  const int q = tid >> 8;     // quarter: cols [64q, 64q+64)

  __shared__ __align__(16) float xs[TT * 4];   // 32 KB: whole x[b]
  __shared__ __align__(16) _Float16 h0L[HH];   // current h0 (f16)
  __shared__ __align__(16) _Float16 h1L[HH];   // current h1 (f16)
  __shared__ float pZ0[4 * HH];  // a-partials, plane per quarter
  __shared__ float pZ1[4 * HH];  // (e+c)-partials
  __shared__ float red[16];
  __shared__ float uL[HH];

  // ---- preload x[b] into LDS (coalesced float4) ----
  const float4* xg = (const float4*)(x + (size_t)b * TT * 4);
  float4* xl = (float4*)xs;
  for (int i = tid; i < TT; i += 1024) xl[i] = xg[i];

  // ---- weight quarter-rows as SSA vectors (96 VGPRs total) ----
  const size_t roff = (size_t)j * HH + q * 64;
  const uvec32 w0  = ld_quarter(Whh0 + roff);
  const uvec32 w1i = ld_quarter(Wih1 + roff);
  const uvec32 w1h = ld_quarter(Whh1 + roff);

  const float4 wx = ((const float4*)Wih0)[j];  // row j of Wih0 (D=4), used by q==0
  const float bias0 = bih0[j] + bhh0[j];
  const float bias1 = bih1[j] + bhh1[j];

  __syncthreads();  // xs ready

  // ---- prologue: h0[0] = tanh(Wih0 x0 + b0), h1[-1] = 0 ----
  if (q == 0) {
    float4 x0v = xl[0];
    float z = wx.x * x0v.x + wx.y * x0v.y + wx.z * x0v.z + wx.w * x0v.w + bias0;
    h0L[j] = (_Float16)tanh_fast(z);
  } else if (q == 1) {
    h1L[j] = (_Float16)0.f;
  }
  __syncthreads();

  const uint4* h0p = (const uint4*)h0L + q * 8;  // quarter of h0 (64 halves)
  const uint4* h1p = (const uint4*)h1L + q * 8;

  float h0T = 0.f;  // q==0: f32 h0[T-1]
  float h1T = 0.f;  // q==1: f32 h1[T-1]

  // ---- fused scan: iteration t computes h1[t] and h0[t+1]; t = 0..T-2 ----
  for (int t = 0; t < TT - 1; ++t) {
    // c = Whh1 quarter . h1[t-1]
    float c0 = 0, c1 = 0, c2 = 0, c3 = 0;
    DOTQ(w1h, h1p, c0, c1, c2, c3);
    float ec = (c0 + c1) + (c2 + c3);
    // shared pass over h0[t]: e (Wih1) and a (Whh0)
    float e0 = 0, e1 = 0, e2 = 0, e3 = 0;
    float a0 = 0, a1 = 0, a2 = 0, a3 = 0;
#pragma unroll
    for (int i = 0; i < 8; ++i) {
      uint4 u = h0p[i];
      e0 = fdot2p(bc2(w1i[4 * i + 0]), bc2(u.x), e0);
      a0 = fdot2p(bc2(w0[4 * i + 0]), bc2(u.x), a0);
      e1 = fdot2p(bc2(w1i[4 * i + 1]), bc2(u.y), e1);
      a1 = fdot2p(bc2(w0[4 * i + 1]), bc2(u.y), a1);
      e2 = fdot2p(bc2(w1i[4 * i + 2]), bc2(u.z), e2);
      a2 = fdot2p(bc2(w0[4 * i + 2]), bc2(u.z), a2);
      e3 = fdot2p(bc2(w1i[4 * i + 3]), bc2(u.w), e3);
      a3 = fdot2p(bc2(w0[4 * i + 3]), bc2(u.w), a3);
    }
    ec += (e0 + e1) + (e2 + e3);
    float a = (a0 + a1) + (a2 + a3);
    pZ0[q * HH + j] = a;   // conflict-free (consecutive lanes, consecutive addrs)
    pZ1[q * HH + j] = ec;
    __syncthreads();
    if (q == 0) {
      float4 xt = xl[t + 1];
      float z0 = pZ0[j] + pZ0[HH + j] + pZ0[2 * HH + j] + pZ0[3 * HH + j] +
                 wx.x * xt.x + wx.y * xt.y + wx.z * xt.z + wx.w * xt.w + bias0;
      h0T = tanh_fast(z0);
      h0L[j] = (_Float16)h0T;
    } else if (q == 1) {
      float z1 = pZ1[j] + pZ1[HH + j] + pZ1[2 * HH + j] + pZ1[3 * HH + j] +
                 bias1;
      h1T = tanh_fast(z1);
      h1L[j] = (_Float16)h1T;
    }
    __syncthreads();
  }

  // ---- final step: h1[T-1] only ----
  {
    float c0 = 0, c1 = 0, c2 = 0, c3 = 0;
    DOTQ(w1h, h1p, c0, c1, c2, c3);
    float e0 = 0, e1 = 0, e2 = 0, e3 = 0;
    DOTQ(w1i, h0p, e0, e1, e2, e3);
    float ec = ((c0 + c1) + (c2 + c3)) + ((e0 + e1) + (e2 + e3));
    pZ1[q * HH + j] = ec;
    __syncthreads();
    if (q == 1) {
      float z1 = pZ1[j] + pZ1[HH + j] + pZ1[2 * HH + j] + pZ1[3 * HH + j] +
                 bias1;
      h1T = tanh_fast(z1);
      h1L[j] = (_Float16)h1T;
    }
    __syncthreads();
  }
  // Now: q==0 threads hold f32 h0T = h0[T-1]; q==1 threads hold f32 h1T.

  // ---- epilogue ----
  const float fw = fcW[j];

  float socb =
      block_sum16(q == 1 ? fw * h1T : 0.f, red, tid) + fcb[0];
  if (tid == 0) out_soc[b] = socb;

  float fsv = (q == 1) ? f2W[j] * (socb * f1W[j] + f1b[j]) : 0.f;
  float fsb = block_sum16(fsv, red, tid) + f2b[0];
  if (tid == 0) ws[64 + b] = fsb;

  // d_soc: u[k] = fcW[k](1-h1T[k]^2); g[h] = sum_k u[k] Wih1[k,h];
  //        dsoc = sum_h g[h] (1-h0T[h]^2) Wih0[h,3]
  if (q == 1) uL[j] = fw * (1.f - h1T * h1T);
  __syncthreads();
  {
    float g = 0.f;
    const int k0 = q * 64;
#pragma unroll 8
    for (int k = 0; k < 64; ++k)
      g += uL[k0 + k] * Wih1[(size_t)(k0 + k) * HH + j];  // coalesced over j
    pZ0[q * HH + j] = g;
  }
  __syncthreads();
  float dsv = 0.f;
  if (q == 0) {
    float g = pZ0[j] + pZ0[HH + j] + pZ0[2 * HH + j] + pZ0[3 * HH + j];
    dsv = g * (1.f - h0T * h0T) * wx.w;
  }
  float dsoc = block_sum16(dsv, red, tid);
  if (tid == 0) ws[b] = dsoc;

  // Up[:, -1]: Ts = sqrt((time[T-1]-time[T-64])/63); hist = sum binom[k+1]*v[T-64+k]
  float histv = 0.f;
  if (tid < WIN) histv = binom[tid + 1] * xs[(TT - WIN + tid) * 4 + 0];
  float hist = block_sum16(histv, red, tid);
  if (tid == 0) {
    float tl = xs[(TT - 1) * 4 + 3], t0v = xs[(TT - WIN) * 4 + 3];
    float tdiff = (tl - t0v) * (1.0f / (float)(WIN - 1));
    float Ts = sqrtf(tdiff);
    float vlast = xs[(TT - 1) * 4 + 0], Ilast = xs[(TT - 1) * 4 + 1];
    float r1 = R1[0], c1v = C1[0];
    float up = -Ts / (r1 * c1v) * vlast + Ts / c1v * Ilast - hist;
    ws[128 + b] = up;
  }
}

__global__ void assemble_kernel(const float* __restrict__ x,
                                const float* __restrict__ Q,
                                const float* __restrict__ delta,
                                const float* __restrict__ R0,
                                const float* __restrict__ ws,
                                float* __restrict__ out) {
  const int i = blockIdx.x;    // row (batch)
  const int jj = threadIdx.x;  // col 0..63
  const float dq = delta[0] / Q[0];
  const size_t base = ((size_t)i * TT + (TT - 1)) * 4;
  const float xv0 = x[base + 0];
  const float xv1 = x[base + 1];
  const float fs = ws[64 + i];
  // loss1[i,j] = delta/Q * x[i,-1,1] + d_soc[j]
  out[64 + i * 64 + jj] = dq * xv1 + ws[jj];
  // loss2[i,j] = f_soc[i] - x[i,-1,0] - R0*x[i,-1,1] - Up_last[j]
  out[64 + 4096 + i * 64 + jj] = fs - xv0 - R0[0] * xv1 - ws[128 + jj];
}

extern "C" void kernel_launch(void* const* d_in, const int* in_sizes, int n_in,
                              void* d_out, int out_size, void* d_ws,
                              size_t ws_size, hipStream_t stream) {
  const float* x    = (const float*)d_in[0];
  const float* Wih0 = (const float*)d_in[1];
  const float* Whh0 = (const float*)d_in[2];
  const float* bih0 = (const float*)d_in[3];
  const float* bhh0 = (const float*)d_in[4];
  const float* Wih1 = (const float*)d_in[5];
  const float* Whh1 = (const float*)d_in[6];
  const float* bih1 = (const float*)d_in[7];
  const float* bhh1 = (const float*)d_in[8];
  const float* fcW  = (const float*)d_in[9];
  const float* fcb  = (const float*)d_in[10];
  const float* Q    = (const float*)d_in[11];
  const float* delta= (const float*)d_in[12];
  const float* f1W  = (const float*)d_in[13];
  const float* f1b  = (const float*)d_in[14];
  const float* f2W  = (const float*)d_in[15];
  const float* f2b  = (const float*)d_in[16];
  // d_in[17] = U0 (unused by reference)
  const float* R0   = (const float*)d_in[18];
  const float* C1   = (const float*)d_in[19];
  const float* R1   = (const float*)d_in[20];
  const float* binom= (const float*)d_in[21];

  float* out = (float*)d_out;
  float* ws  = (float*)d_ws;

  hipLaunchKernelGGL(rnn_chain_kernel, dim3(64), dim3(1024), 0, stream, x,
                     Wih0, Whh0, bih0, bhh0, Wih1, Whh1, bih1, bhh1, fcW, fcb,
                     f1W, f1b, f2W, f2b, C1, R1, binom, out, ws);
  hipLaunchKernelGGL(assemble_kernel, dim3(64), dim3(64), 0, stream, x, Q,
                     delta, R0, ws, out);
}

// Round 7
// 2750.322 us; speedup vs baseline: 5.3435x; 1.0482x over previous
//
#include <hip/hip_runtime.h>

// Fsmm_rnn: 2-layer tanh RNN (B=64,T=2048,D=4,H=256) + closed-form last-step
// grad + fractional-memory Up at t=T-1 + (64,64) broadcast assemblies.
//
// v5 (resubmit — R6 was an infra container failure, no data).
// Post-mortem law (v1/v2/v3/v4): backend budgets VGPRs for 2 blocks/CU by
// default (256thr->256cap/208used, 512thr->128, 1024thr->64) regardless of
// launch_bounds arg2 / amdgpu_waves_per_eu. v4 demand ~121 > 64 -> spill
// (WRITE_SIZE=23MB scratch). Fix: static LDS ~102KB > 80KB forces max 1
// workgroup/CU in the backend's occupancy calc -> 16 waves/CU -> 4 waves/EU
// -> 128-VGPR budget. Demand 96 weight uints (3 SSA uvec32) + ~25 working
// fits. Occupancy per chip unchanged (64 blocks over 256 CUs).

#define TT 2048
#define HH 256
#define WIN 64

typedef _Float16 h2 __attribute__((ext_vector_type(2)));
typedef uint uvec32 __attribute__((ext_vector_type(32)));

__device__ __forceinline__ float fdot2p(h2 a, h2 b, float c) {
  return __builtin_amdgcn_fdot2(a, b, c, false);
}
__device__ __forceinline__ h2 bc2(unsigned u) {
  return __builtin_bit_cast(h2, u);
}

__device__ __forceinline__ float tanh_fast(float x) {
  float xc = fminf(fmaxf(x, -15.f), 15.f);
  float e = __expf(2.f * xc);
  return (e - 1.f) * __builtin_amdgcn_rcpf(e + 1.f);
}

// 1024-thread (16-wave) block sum, broadcast to all threads.
__device__ __forceinline__ float block_sum16(float v, float* red, int tid) {
#pragma unroll
  for (int off = 32; off >= 1; off >>= 1) v += __shfl_down(v, off, 64);
  __syncthreads();  // protect red reuse across calls
  if ((tid & 63) == 0) red[tid >> 6] = v;
  __syncthreads();
  float s = 0.f;
#pragma unroll
  for (int w = 0; w < 16; ++w) s += red[w];
  return s;
}

// Load+convert a 64-col quarter row (f32 global) into packed-h2 uvec32 (32 VGPRs).
__device__ __forceinline__ uvec32 ld_quarter(const float* __restrict__ base) {
  uvec32 w;
  const float4* g = (const float4*)base;
#pragma unroll
  for (int i = 0; i < 16; ++i) {
    float4 a = g[i];
    h2 t0; t0.x = (_Float16)a.x; t0.y = (_Float16)a.y;
    h2 t1; t1.x = (_Float16)a.z; t1.y = (_Float16)a.w;
    w[2 * i] = __builtin_bit_cast(uint, t0);
    w[2 * i + 1] = __builtin_bit_cast(uint, t1);
  }
  return w;
}

// 64-col quarter dot vs broadcast h vector (8 uint4 uniform LDS reads).
#define DOTQ(WV, HP, A0, A1, A2, A3)                                       \
  {                                                                        \
    _Pragma("unroll") for (int _i = 0; _i < 8; ++_i) {                     \
      uint4 _u = (HP)[_i];                                                 \
      A0 = fdot2p(bc2(WV[4 * _i + 0]), bc2(_u.x), A0);                     \
      A1 = fdot2p(bc2(WV[4 * _i + 1]), bc2(_u.y), A1);                     \
      A2 = fdot2p(bc2(WV[4 * _i + 2]), bc2(_u.z), A2);                     \
      A3 = fdot2p(bc2(WV[4 * _i + 3]), bc2(_u.w), A3);                     \
    }                                                                      \
  }

__global__ __launch_bounds__(1024, 1) void rnn_chain_kernel(
    const float* __restrict__ x, const float* __restrict__ Wih0,
    const float* __restrict__ Whh0, const float* __restrict__ bih0,
    const float* __restrict__ bhh0, const float* __restrict__ Wih1,
    const float* __restrict__ Whh1, const float* __restrict__ bih1,
    const float* __restrict__ bhh1, const float* __restrict__ fcW,
    const float* __restrict__ fcb, const float* __restrict__ f1W,
    const float* __restrict__ f1b, const float* __restrict__ f2W,
    const float* __restrict__ f2b, const float* __restrict__ C1,
    const float* __restrict__ R1, const float* __restrict__ binom,
    float* __restrict__ out_soc,  // d_out[0..64)
    float* __restrict__ ws)       // [0..64) d_soc, [64..128) f_soc, [128..192) Up_last
{
  const int b = blockIdx.x;
  const int tid = threadIdx.x;
  const int j = tid & 255;    // row
  const int q = tid >> 8;     // quarter: cols [64q, 64q+64)

  __shared__ __align__(16) float xs[TT * 4];   // 32 KB: whole x[b]
  __shared__ __align__(16) _Float16 h0L[HH];   // current h0 (f16)
  __shared__ __align__(16) _Float16 h1L[HH];   // current h1 (f16)
  __shared__ float pZ0[4 * HH];  // a-partials, plane per quarter
  __shared__ float pZ1[4 * HH];  // (e+c)-partials
  __shared__ float red[16];
  __shared__ float uL[HH];
  // Occupancy forcing pad: lifts static LDS to ~102KB so the backend's
  // occupancy model sees max 1 workgroup/CU -> 4 waves/EU -> 128-VGPR budget.
  __shared__ float occ_pad[16384];  // 64 KB

  // ---- preload x[b] into LDS (coalesced float4) ----
  const float4* xg = (const float4*)(x + (size_t)b * TT * 4);
  float4* xl = (float4*)xs;
  for (int i = tid; i < TT; i += 1024) xl[i] = xg[i];

  // ---- weight quarter-rows as SSA vectors (96 VGPRs total) ----
  const size_t roff = (size_t)j * HH + q * 64;
  const uvec32 w0  = ld_quarter(Whh0 + roff);
  const uvec32 w1i = ld_quarter(Wih1 + roff);
  const uvec32 w1h = ld_quarter(Whh1 + roff);

  const float4 wx = ((const float4*)Wih0)[j];  // row j of Wih0 (D=4), used by q==0
  const float bias0 = bih0[j] + bhh0[j];
  const float bias1 = bih1[j] + bhh1[j];

  __syncthreads();  // xs ready

  // keep occ_pad alive (one dead-cheap volatile store; tid==1023 exists)
  if (tid == 1023) ((volatile float*)occ_pad)[0] = xs[0];

  // ---- prologue: h0[0] = tanh(Wih0 x0 + b0), h1[-1] = 0 ----
  if (q == 0) {
    float4 x0v = xl[0];
    float z = wx.x * x0v.x + wx.y * x0v.y + wx.z * x0v.z + wx.w * x0v.w + bias0;
    h0L[j] = (_Float16)tanh_fast(z);
  } else if (q == 1) {
    h1L[j] = (_Float16)0.f;
  }
  __syncthreads();

  const uint4* h0p = (const uint4*)h0L + q * 8;  // quarter of h0 (64 halves)
  const uint4* h1p = (const uint4*)h1L + q * 8;

  float h0T = 0.f;  // q==0: f32 h0[T-1]
  float h1T = 0.f;  // q==1: f32 h1[T-1]

  // ---- fused scan: iteration t computes h1[t] and h0[t+1]; t = 0..T-2 ----
  for (int t = 0; t < TT - 1; ++t) {
    // c = Whh1 quarter . h1[t-1]
    float c0 = 0, c1 = 0, c2 = 0, c3 = 0;
    DOTQ(w1h, h1p, c0, c1, c2, c3);
    float ec = (c0 + c1) + (c2 + c3);
    // shared pass over h0[t]: e (Wih1) and a (Whh0)
    float e0 = 0, e1 = 0, e2 = 0, e3 = 0;
    float a0 = 0, a1 = 0, a2 = 0, a3 = 0;
#pragma unroll
    for (int i = 0; i < 8; ++i) {
      uint4 u = h0p[i];
      e0 = fdot2p(bc2(w1i[4 * i + 0]), bc2(u.x), e0);
      a0 = fdot2p(bc2(w0[4 * i + 0]), bc2(u.x), a0);
      e1 = fdot2p(bc2(w1i[4 * i + 1]), bc2(u.y), e1);
      a1 = fdot2p(bc2(w0[4 * i + 1]), bc2(u.y), a1);
      e2 = fdot2p(bc2(w1i[4 * i + 2]), bc2(u.z), e2);
      a2 = fdot2p(bc2(w0[4 * i + 2]), bc2(u.z), a2);
      e3 = fdot2p(bc2(w1i[4 * i + 3]), bc2(u.w), e3);
      a3 = fdot2p(bc2(w0[4 * i + 3]), bc2(u.w), a3);
    }
    ec += (e0 + e1) + (e2 + e3);
    float a = (a0 + a1) + (a2 + a3);
    pZ0[q * HH + j] = a;   // conflict-free (consecutive lanes, consecutive addrs)
    pZ1[q * HH + j] = ec;
    __syncthreads();
    if (q == 0) {
      float4 xt = xl[t + 1];
      float z0 = pZ0[j] + pZ0[HH + j] + pZ0[2 * HH + j] + pZ0[3 * HH + j] +
                 wx.x * xt.x + wx.y * xt.y + wx.z * xt.z + wx.w * xt.w + bias0;
      h0T = tanh_fast(z0);
      h0L[j] = (_Float16)h0T;
    } else if (q == 1) {
      float z1 = pZ1[j] + pZ1[HH + j] + pZ1[2 * HH + j] + pZ1[3 * HH + j] +
                 bias1;
      h1T = tanh_fast(z1);
      h1L[j] = (_Float16)h1T;
    }
    __syncthreads();
  }

  // ---- final step: h1[T-1] only ----
  {
    float c0 = 0, c1 = 0, c2 = 0, c3 = 0;
    DOTQ(w1h, h1p, c0, c1, c2, c3);
    float e0 = 0, e1 = 0, e2 = 0, e3 = 0;
    DOTQ(w1i, h0p, e0, e1, e2, e3);
    float ec = ((c0 + c1) + (c2 + c3)) + ((e0 + e1) + (e2 + e3));
    pZ1[q * HH + j] = ec;
    __syncthreads();
    if (q == 1) {
      float z1 = pZ1[j] + pZ1[HH + j] + pZ1[2 * HH + j] + pZ1[3 * HH + j] +
                 bias1;
      h1T = tanh_fast(z1);
      h1L[j] = (_Float16)h1T;
    }
    __syncthreads();
  }
  // Now: q==0 threads hold f32 h0T = h0[T-1]; q==1 threads hold f32 h1T.

  // ---- epilogue ----
  const float fw = fcW[j];

  float socb =
      block_sum16(q == 1 ? fw * h1T : 0.f, red, tid) + fcb[0];
  if (tid == 0) out_soc[b] = socb;

  float fsv = (q == 1) ? f2W[j] * (socb * f1W[j] + f1b[j]) : 0.f;
  float fsb = block_sum16(fsv, red, tid) + f2b[0];
  if (tid == 0) ws[64 + b] = fsb;

  // d_soc: u[k] = fcW[k](1-h1T[k]^2); g[h] = sum_k u[k] Wih1[k,h];
  //        dsoc = sum_h g[h] (1-h0T[h]^2) Wih0[h,3]
  if (q == 1) uL[j] = fw * (1.f - h1T * h1T);
  __syncthreads();
  {
    float g = 0.f;
    const int k0 = q * 64;
#pragma unroll 8
    for (int k = 0; k < 64; ++k)
      g += uL[k0 + k] * Wih1[(size_t)(k0 + k) * HH + j];  // coalesced over j
    pZ0[q * HH + j] = g;
  }
  __syncthreads();
  float dsv = 0.f;
  if (q == 0) {
    float g = pZ0[j] + pZ0[HH + j] + pZ0[2 * HH + j] + pZ0[3 * HH + j];
    dsv = g * (1.f - h0T * h0T) * wx.w;
  }
  float dsoc = block_sum16(dsv, red, tid);
  if (tid == 0) ws[b] = dsoc;

  // Up[:, -1]: Ts = sqrt((time[T-1]-time[T-64])/63); hist = sum binom[k+1]*v[T-64+k]
  float histv = 0.f;
  if (tid < WIN) histv = binom[tid + 1] * xs[(TT - WIN + tid) * 4 + 0];
  float hist = block_sum16(histv, red, tid);
  if (tid == 0) {
    float tl = xs[(TT - 1) * 4 + 3], t0v = xs[(TT - WIN) * 4 + 3];
    float tdiff = (tl - t0v) * (1.0f / (float)(WIN - 1));
    float Ts = sqrtf(tdiff);
    float vlast = xs[(TT - 1) * 4 + 0], Ilast = xs[(TT - 1) * 4 + 1];
    float r1 = R1[0], c1v = C1[0];
    float up = -Ts / (r1 * c1v) * vlast + Ts / c1v * Ilast - hist;
    ws[128 + b] = up;
  }
}

__global__ void assemble_kernel(const float* __restrict__ x,
                                const float* __restrict__ Q,
                                const float* __restrict__ delta,
                                const float* __restrict__ R0,
                                const float* __restrict__ ws,
                                float* __restrict__ out) {
  const int i = blockIdx.x;    // row (batch)
  const int jj = threadIdx.x;  // col 0..63
  const float dq = delta[0] / Q[0];
  const size_t base = ((size_t)i * TT + (TT - 1)) * 4;
  const float xv0 = x[base + 0];
  const float xv1 = x[base + 1];
  const float fs = ws[64 + i];
  // loss1[i,j] = delta/Q * x[i,-1,1] + d_soc[j]
  out[64 + i * 64 + jj] = dq * xv1 + ws[jj];
  // loss2[i,j] = f_soc[i] - x[i,-1,0] - R0*x[i,-1,1] - Up_last[j]
  out[64 + 4096 + i * 64 + jj] = fs - xv0 - R0[0] * xv1 - ws[128 + jj];
}

extern "C" void kernel_launch(void* const* d_in, const int* in_sizes, int n_in,
                              void* d_out, int out_size, void* d_ws,
                              size_t ws_size, hipStream_t stream) {
  const float* x    = (const float*)d_in[0];
  const float* Wih0 = (const float*)d_in[1];
  const float* Whh0 = (const float*)d_in[2];
  const float* bih0 = (const float*)d_in[3];
  const float* bhh0 = (const float*)d_in[4];
  const float* Wih1 = (const float*)d_in[5];
  const float* Whh1 = (const float*)d_in[6];
  const float* bih1 = (const float*)d_in[7];
  const float* bhh1 = (const float*)d_in[8];
  const float* fcW  = (const float*)d_in[9];
  const float* fcb  = (const float*)d_in[10];
  const float* Q    = (const float*)d_in[11];
  const float* delta= (const float*)d_in[12];
  const float* f1W  = (const float*)d_in[13];
  const float* f1b  = (const float*)d_in[14];
  const float* f2W  = (const float*)d_in[15];
  const float* f2b  = (const float*)d_in[16];
  // d_in[17] = U0 (unused by reference)
  const float* R0   = (const float*)d_in[18];
  const float* C1   = (const float*)d_in[19];
  const float* R1   = (const float*)d_in[20];
  const float* binom= (const float*)d_in[21];

  float* out = (float*)d_out;
  float* ws  = (float*)d_ws;

  hipLaunchKernelGGL(rnn_chain_kernel, dim3(64), dim3(1024), 0, stream, x,
                     Wih0, Whh0, bih0, bhh0, Wih1, Whh1, bih1, bhh1, fcW, fcb,
                     f1W, f1b, f2W, f2b, C1, R1, binom, out, ws);
  hipLaunchKernelGGL(assemble_kernel, dim3(64), dim3(64), 0, stream, x, Q,
                     delta, R0, ws, out);
}